// Round 8
// baseline (610.292 us; speedup 1.0000x reference)
//
#include <hip/hip_runtime.h>
#include <cstddef>
#include <cstdint>

// RSABlock: conv_offset_mask (3x3) -> DCNv2 -> leaky_relu -> conv3x3 -> +x.
// B=2, C=32, H=W=256, DG=8, K=9, om channels = 216.
//
// Round 8: dcn 8 sub-threads per pixel (1 group each), wave = 8px x 8subs,
// grid rows*8 = 8192 waves (fills all wave slots; was grid-capped at 50%).
// Dense convs stay bf16-MFMA.

#define CH 32
#define HH 256
#define WW 256
#define BB 2
#define HW (HH * WW)
#define OMC 216
#define NEG_SLOPE 0.2f

typedef __attribute__((ext_vector_type(8))) short short8;
typedef __attribute__((ext_vector_type(4))) float f32x4;
typedef __attribute__((ext_vector_type(4))) unsigned int u32x4;
typedef __attribute__((ext_vector_type(2))) unsigned int u32x2;

#define WPK_OFF_N (9 * 16 * 16 * 32)  // 73728
#define WPK_C1_N  (9 * 2 * 16 * 32)   // 9216
#define WTDCN_N   (288 * 32)          // 9216

__device__ __forceinline__ uint16_t f2bf(float f) {  // RNE fp32->bf16
    union { float f; uint32_t u; } x; x.f = f;
    const uint32_t r = x.u + 0x7fffu + ((x.u >> 16) & 1u);
    return (uint16_t)(r >> 16);
}
__device__ __forceinline__ float bf2f(uint32_t h) {  // low 16 bits -> fp32
    union { uint32_t u; float f; } x; x.u = h << 16; return x.f;
}

// ---------------------------------------------------------------------------
// pack_px: [32][HW] f32 -> [HW][32] bf16. blockIdx.y: 0,1 = x b0,b1; 2,3 = off.
// ---------------------------------------------------------------------------
__global__ __launch_bounds__(256) void pack_px(
    const float* __restrict__ x, const float* __restrict__ off,
    uint16_t* __restrict__ xpk, uint16_t* __restrict__ offpk)
{
    const int z = blockIdx.y;
    const float* src = (z < 2) ? (x + (size_t)z * CH * HW)
                               : (off + (size_t)(z - 2) * CH * HW);
    uint16_t* dst = (z < 2) ? (xpk + (size_t)z * HW * CH)
                            : (offpk + (size_t)(z - 2) * HW * CH);
    const int px = blockIdx.x * 256 + threadIdx.x;
    uint32_t w[16];
    #pragma unroll
    for (int c = 0; c < CH; c += 2) {
        const float a = src[(size_t)c * HW + px];
        const float b = src[(size_t)(c + 1) * HW + px];
        w[c >> 1] = (uint32_t)f2bf(a) | ((uint32_t)f2bf(b) << 16);
    }
    u32x4* d = (u32x4*)(dst + (size_t)px * CH);
    #pragma unroll
    for (int i = 0; i < 4; i++) {
        u32x4 v = { w[4 * i], w[4 * i + 1], w[4 * i + 2], w[4 * i + 3] };
        d[i] = v;
    }
}

// ---------------------------------------------------------------------------
// pack_w: weight repacks. Inputs OIHW, t = kh*3+kw.
// ---------------------------------------------------------------------------
__global__ __launch_bounds__(256) void pack_w(
    const float* __restrict__ w_off, const float* __restrict__ w_c1,
    const float* __restrict__ w_dcn,
    uint16_t* __restrict__ wpk_off, uint16_t* __restrict__ wpk_c1,
    float* __restrict__ wt_dcn)
{
    const int i = blockIdx.x * 256 + threadIdx.x;
    if (i < WPK_OFF_N) {
        const int ic = i & 31, r = (i >> 5) & 15, mt = (i >> 9) & 15, t = i >> 13;
        const int oc = mt * 16 + r;
        const float v = (oc < OMC) ? w_off[((size_t)oc * CH + ic) * 9 + t] : 0.f;
        wpk_off[i] = f2bf(v);
    } else if (i < WPK_OFF_N + WPK_C1_N) {
        const int j = i - WPK_OFF_N;
        const int ic = j & 31, r = (j >> 5) & 15, mt = (j >> 9) & 1, t = j >> 10;
        const int oc = mt * 16 + r;
        wpk_c1[j] = f2bf(w_c1[((size_t)oc * CH + ic) * 9 + t]);
    } else if (i < WPK_OFF_N + WPK_C1_N + WTDCN_N) {
        const int j = i - (WPK_OFF_N + WPK_C1_N);
        const int o = j & 31, row = j >> 5;          // row = ic*9 + k
        wt_dcn[j] = w_dcn[(size_t)o * 288 + row];
    }
}

// ---------------------------------------------------------------------------
// conv_off_mfma: block = 4 rows x 16 cols output, all 256 (padded) oc.
// ---------------------------------------------------------------------------
__global__ __launch_bounds__(256) void conv_off_mfma(
    const uint16_t* __restrict__ inpk,  // [HW][32] bf16 (offset, batch base)
    const uint16_t* __restrict__ wpk,   // [9][16][16][32] bf16
    const float* __restrict__ bias,     // [216]
    float* __restrict__ om,             // [216][rows][256] f32
    int r0, int rows)
{
    __shared__ __align__(16) uint16_t tile[6 * 18 * 40];  // 8640 B

    const int gy0 = r0 + blockIdx.y * 4 - 1;
    const int gx0 = blockIdx.x * 16 - 1;
    for (int chunk = threadIdx.x; chunk < 6 * 18 * 4; chunk += 256) {
        const int rec = chunk >> 2, part = chunk & 3;
        const int rr = rec / 18, rc = rec - rr * 18;
        const int gy = gy0 + rr, gx = gx0 + rc;
        u32x4 v = {0u, 0u, 0u, 0u};
        if ((unsigned)gy < (unsigned)HH && (unsigned)gx < (unsigned)WW)
            v = *(const u32x4*)(inpk + ((size_t)gy * WW + gx) * CH + part * 8);
        *(u32x4*)((char*)tile + rec * 80 + part * 16) = v;
    }
    __syncthreads();

    const int lane = threadIdx.x & 63;
    const int wave = threadIdx.x >> 6;
    const int tx = lane & 15;
    const int q  = lane >> 4;

    f32x4 acc[4][4];
    #pragma unroll
    for (int m = 0; m < 4; m++)
        #pragma unroll
        for (int n = 0; n < 4; n++) acc[m][n] = (f32x4){0.f, 0.f, 0.f, 0.f};

    #pragma unroll
    for (int t = 0; t < 9; t++) {
        const int kh = t / 3, kw = t - kh * 3;
        short8 bfr[4], afr[4];
        #pragma unroll
        for (int n = 0; n < 4; n++)
            bfr[n] = *(const short8*)((const char*)tile +
                       ((n + kh) * 18 + (tx + kw)) * 80 + q * 16);
        #pragma unroll
        for (int m = 0; m < 4; m++) {
            const int mt = wave * 4 + m;
            afr[m] = *(const short8*)(wpk +
                       (((size_t)t * 16 + mt) * 16 + tx) * 32 + q * 8);
        }
        #pragma unroll
        for (int m = 0; m < 4; m++)
            #pragma unroll
            for (int n = 0; n < 4; n++)
                acc[m][n] = __builtin_amdgcn_mfma_f32_16x16x32_bf16(
                    afr[m], bfr[n], acc[m][n], 0, 0, 0);
    }

    const int srW = rows * WW;
    const int gx = blockIdx.x * 16 + tx;
    #pragma unroll
    for (int m = 0; m < 4; m++) {
        const int mt = wave * 4 + m;
        #pragma unroll
        for (int n = 0; n < 4; n++) {
            const int hr = blockIdx.y * 4 + n;
            #pragma unroll
            for (int i = 0; i < 4; i++) {
                const int oc = mt * 16 + q * 4 + i;
                if (oc < OMC)
                    om[(size_t)oc * srW + hr * WW + gx] = acc[m][n][i] + bias[oc];
            }
        }
    }
}

// ---------------------------------------------------------------------------
// conv_c1_mfma: block = 8 rows x 16 cols, M=32 (2 m-tiles). Fused bias+resid.
// ---------------------------------------------------------------------------
__global__ __launch_bounds__(256) void conv_c1_mfma(
    const uint16_t* __restrict__ feapk, // [HW][32] bf16 batch base
    const uint16_t* __restrict__ wpk,   // [9][2][16][32] bf16
    const float* __restrict__ bias,     // [32]
    const float* __restrict__ resid,    // [32][HW] f32 batch base (x)
    float* __restrict__ out)            // [32][HW] f32 batch base
{
    __shared__ __align__(16) uint16_t tile[10 * 18 * 40];  // 14400 B

    const int gy0 = blockIdx.y * 8 - 1;
    const int gx0 = blockIdx.x * 16 - 1;
    for (int chunk = threadIdx.x; chunk < 10 * 18 * 4; chunk += 256) {
        const int rec = chunk >> 2, part = chunk & 3;
        const int rr = rec / 18, rc = rec - rr * 18;
        const int gy = gy0 + rr, gx = gx0 + rc;
        u32x4 v = {0u, 0u, 0u, 0u};
        if ((unsigned)gy < (unsigned)HH && (unsigned)gx < (unsigned)WW)
            v = *(const u32x4*)(feapk + ((size_t)gy * WW + gx) * CH + part * 8);
        *(u32x4*)((char*)tile + rec * 80 + part * 16) = v;
    }
    __syncthreads();

    const int lane = threadIdx.x & 63;
    const int wave = threadIdx.x >> 6;
    const int tx = lane & 15;
    const int q  = lane >> 4;
    const int mt = wave & 1;
    const int nb = (wave >> 1) * 4;

    f32x4 acc[4];
    #pragma unroll
    for (int n = 0; n < 4; n++) acc[n] = (f32x4){0.f, 0.f, 0.f, 0.f};

    #pragma unroll
    for (int t = 0; t < 9; t++) {
        const int kh = t / 3, kw = t - kh * 3;
        const short8 afr = *(const short8*)(wpk +
                             (((size_t)t * 2 + mt) * 16 + tx) * 32 + q * 8);
        #pragma unroll
        for (int n = 0; n < 4; n++) {
            const short8 bfr = *(const short8*)((const char*)tile +
                                 ((nb + n + kh) * 18 + (tx + kw)) * 80 + q * 16);
            acc[n] = __builtin_amdgcn_mfma_f32_16x16x32_bf16(
                afr, bfr, acc[n], 0, 0, 0);
        }
    }

    const int gx = blockIdx.x * 16 + tx;
    #pragma unroll
    for (int n = 0; n < 4; n++) {
        const int gy = blockIdx.y * 8 + nb + n;
        #pragma unroll
        for (int i = 0; i < 4; i++) {
            const int oc = mt * 16 + q * 4 + i;
            const size_t idx = (size_t)oc * HW + (size_t)gy * WW + gx;
            out[idx] = acc[n][i] + bias[oc] + resid[idx];
        }
    }
}

// ---------------------------------------------------------------------------
// dcn_kernel v3: 8 sub-threads per pixel (1 deformable group each);
// wave = 8 px x 8 subs; acc[32] reduced via shfl_xor(8,16,32).
// Grid: rows*8 blocks of 256 (32 px/block) -> 8192 waves/launch.
// ---------------------------------------------------------------------------
__global__ __launch_bounds__(256, 8) void dcn_kernel(
    const uint16_t* __restrict__ xpk,   // [HW][32] bf16 batch base
    const float* __restrict__ om,       // [216][rows][256] f32
    const float* __restrict__ wt,       // [288][32] f32, row = ic*9+k
    const float* __restrict__ b_dcn,    // [32]
    uint16_t* __restrict__ feapk,       // [HW][32] bf16 batch base
    int r0, int rows)
{
    const int lane = threadIdx.x & 63;
    const int wave = threadIdx.x >> 6;
    const int g    = lane >> 3;                 // sub = deformable group 0..7
    const int p    = blockIdx.x * 32 + (wave << 3) + (lane & 7);
    const int hr = p >> 8;
    const int wx = p & 255;
    const int h  = r0 + hr;
    const int srW = rows * WW;

    float acc[CH];
    #pragma unroll
    for (int o = 0; o < CH; o++) acc[o] = 0.f;

    #pragma unroll 3
    for (int k = 0; k < 9; k++) {
        const int ch = g * 9 + k;
        const float dy = om[(size_t)ch * srW + p];
        const float dx = om[(size_t)(72 + ch) * srW + p];
        const float mm = om[(size_t)(144 + ch) * srW + p];
        const float mask = 1.f / (1.f + __expf(-mm));

        const float py = dy + (float)(h + k / 3 - 1);
        const float px = dx + (float)(wx + k % 3 - 1);
        const float y0f = floorf(py), x0f = floorf(px);
        const int y0 = (int)y0f, x0 = (int)x0f;
        const float ly = py - y0f, lx = px - x0f;

        float w00 = (1.f - ly) * (1.f - lx), w01 = (1.f - ly) * lx;
        float w10 = ly * (1.f - lx),         w11 = ly * lx;
        if (!((unsigned)y0       < (unsigned)HH && (unsigned)x0       < (unsigned)WW)) w00 = 0.f;
        if (!((unsigned)y0       < (unsigned)HH && (unsigned)(x0 + 1) < (unsigned)WW)) w01 = 0.f;
        if (!((unsigned)(y0 + 1) < (unsigned)HH && (unsigned)x0       < (unsigned)WW)) w10 = 0.f;
        if (!((unsigned)(y0 + 1) < (unsigned)HH && (unsigned)(x0 + 1) < (unsigned)WW)) w11 = 0.f;
        w00 *= mask; w01 *= mask; w10 *= mask; w11 *= mask;

        const int cy0 = min(max(y0, 0), HH - 1), cy1 = min(max(y0 + 1, 0), HH - 1);
        const int cx0 = min(max(x0, 0), WW - 1), cx1 = min(max(x0 + 1, 0), WW - 1);

        const u32x2 v00 = *(const u32x2*)(xpk + ((size_t)cy0 * WW + cx0) * CH + g * 4);
        const u32x2 v01 = *(const u32x2*)(xpk + ((size_t)cy0 * WW + cx1) * CH + g * 4);
        const u32x2 v10 = *(const u32x2*)(xpk + ((size_t)cy1 * WW + cx0) * CH + g * 4);
        const u32x2 v11 = *(const u32x2*)(xpk + ((size_t)cy1 * WW + cx1) * CH + g * 4);

        #pragma unroll
        for (int c = 0; c < 4; c++) {
            const int sh = (c & 1) * 16;
            const int wi = c >> 1;
            const float f00 = bf2f((v00[wi] >> sh) & 0xffffu);
            const float f01 = bf2f((v01[wi] >> sh) & 0xffffu);
            const float f10 = bf2f((v10[wi] >> sh) & 0xffffu);
            const float f11 = bf2f((v11[wi] >> sh) & 0xffffu);
            const float v = w00 * f00 + w01 * f01 + w10 * f10 + w11 * f11;
            const float* wrow = wt + (size_t)((g * 4 + c) * 9 + k) * CH;
            #pragma unroll
            for (int o = 0; o < CH; o++)
                acc[o] = fmaf(wrow[o], v, acc[o]);
        }
    }

    // reduce partial acc across the 8 subs (lanes ^8, ^16, ^32)
    #pragma unroll
    for (int o = 0; o < CH; o++) {
        acc[o] += __shfl_xor(acc[o], 8, 64);
        acc[o] += __shfl_xor(acc[o], 16, 64);
        acc[o] += __shfl_xor(acc[o], 32, 64);
    }

    if (g == 0) {
        uint32_t wout[16];
        #pragma unroll
        for (int o = 0; o < CH; o += 2) {
            float v0 = acc[o] + b_dcn[o];         v0 = v0 > 0.f ? v0 : NEG_SLOPE * v0;
            float v1 = acc[o + 1] + b_dcn[o + 1]; v1 = v1 > 0.f ? v1 : NEG_SLOPE * v1;
            wout[o >> 1] = (uint32_t)f2bf(v0) | ((uint32_t)f2bf(v1) << 16);
        }
        u32x4* d = (u32x4*)(feapk + ((size_t)h * WW + wx) * CH);
        #pragma unroll
        for (int i = 0; i < 4; i++) {
            u32x4 v = { wout[4 * i], wout[4 * i + 1], wout[4 * i + 2], wout[4 * i + 3] };
            d[i] = v;
        }
    }
}

extern "C" void kernel_launch(void* const* d_in, const int* in_sizes, int n_in,
                              void* d_out, int out_size, void* d_ws, size_t ws_size,
                              hipStream_t stream) {
    const float* x      = (const float*)d_in[0];
    const float* offset = (const float*)d_in[1];
    const float* w_off  = (const float*)d_in[2];
    const float* b_off  = (const float*)d_in[3];
    const float* w_dcn  = (const float*)d_in[4];
    const float* b_dcn  = (const float*)d_in[5];
    const float* w_c1   = (const float*)d_in[6];
    const float* b_c1   = (const float*)d_in[7];
    float* out = (float*)d_out;

    auto aup = [](size_t v) { return (v + 255) & ~(size_t)255; };
    char* wsp = (char*)d_ws;
    uint16_t* xpk    = (uint16_t*)wsp; wsp += aup((size_t)BB * HW * CH * 2);
    uint16_t* offpk  = (uint16_t*)wsp; wsp += aup((size_t)BB * HW * CH * 2);
    uint16_t* feapk  = (uint16_t*)wsp; wsp += aup((size_t)BB * HW * CH * 2);
    uint16_t* wpkoff = (uint16_t*)wsp; wsp += aup((size_t)WPK_OFF_N * 2);
    uint16_t* wpkc1  = (uint16_t*)wsp; wsp += aup((size_t)WPK_C1_N * 2);
    float*    wtdcn  = (float*)wsp;    wsp += aup((size_t)WTDCN_N * 4);
    float*    om     = (float*)wsp;
    const size_t used = (size_t)(wsp - (char*)d_ws);

    const size_t row_bytes = (size_t)OMC * WW * sizeof(float);  // 221184
    const size_t avail = (ws_size > used) ? (ws_size - used) : 0;
    int rows_per = (int)(avail / row_bytes) & ~3;   // multiple of 4
    if (rows_per < 4)  rows_per = 4;
    if (rows_per > HH) rows_per = HH;

    // 0) packs
    pack_px<<<dim3(HW / 256, 4), dim3(256), 0, stream>>>(x, offset, xpk, offpk);
    const int wn = WPK_OFF_N + WPK_C1_N + WTDCN_N;
    pack_w<<<dim3((wn + 255) / 256), dim3(256), 0, stream>>>(
        w_off, w_c1, w_dcn, wpkoff, wpkc1, wtdcn);

    // 1+2) per batch, per row-stripe: conv_off (MFMA) -> om, dcn -> feapk
    for (int b = 0; b < BB; b++) {
        const uint16_t* offb = offpk + (size_t)b * HW * CH;
        const uint16_t* xb   = xpk   + (size_t)b * HW * CH;
        uint16_t*       feab = feapk + (size_t)b * HW * CH;
        for (int r0 = 0; r0 < HH; r0 += rows_per) {
            const int rows = (r0 + rows_per <= HH) ? rows_per : (HH - r0);
            conv_off_mfma<<<dim3(WW / 16, rows / 4), dim3(256), 0, stream>>>(
                offb, wpkoff, b_off, om, r0, rows);
            dcn_kernel<<<dim3(rows * 8), dim3(256), 0, stream>>>(
                xb, om, wtdcn, b_dcn, feab, r0, rows);
        }
    }

    // 3) conv c1 (MFMA) + bias + residual
    for (int b = 0; b < BB; b++) {
        conv_c1_mfma<<<dim3(WW / 16, HH / 8), dim3(256), 0, stream>>>(
            feapk + (size_t)b * HW * CH, wpkc1, b_c1,
            x + (size_t)b * CH * HW, out + (size_t)b * CH * HW);
    }
}

// Round 9
// 476.352 us; speedup vs baseline: 1.2812x; 1.2812x over previous
//
#include <hip/hip_runtime.h>
#include <cstddef>
#include <cstdint>

// RSABlock: conv_offset_mask (3x3) -> DCNv2 -> leaky_relu -> conv3x3 -> +x.
// B=2, C=32, H=W=256, DG=8, K=9, om channels = 216.
//
// Round 9: dcn 8 subs/pixel as round 8, but __launch_bounds__(256,6):
// round 8's (256,8) forced a 64-VGPR cap -> acc[32] spilled to scratch
// (WRITE_SIZE 4->333MB, the regression). 85-VGPR budget removes the spill;
// 6 waves/SIMD resident = 75% occupancy (v2 was grid-capped at 50%).

#define CH 32
#define HH 256
#define WW 256
#define BB 2
#define HW (HH * WW)
#define OMC 216
#define NEG_SLOPE 0.2f

typedef __attribute__((ext_vector_type(8))) short short8;
typedef __attribute__((ext_vector_type(4))) float f32x4;
typedef __attribute__((ext_vector_type(4))) unsigned int u32x4;
typedef __attribute__((ext_vector_type(2))) unsigned int u32x2;

#define WPK_OFF_N (9 * 16 * 16 * 32)  // 73728
#define WPK_C1_N  (9 * 2 * 16 * 32)   // 9216
#define WTDCN_N   (288 * 32)          // 9216

__device__ __forceinline__ uint16_t f2bf(float f) {  // RNE fp32->bf16
    union { float f; uint32_t u; } x; x.f = f;
    const uint32_t r = x.u + 0x7fffu + ((x.u >> 16) & 1u);
    return (uint16_t)(r >> 16);
}
__device__ __forceinline__ float bf2f(uint32_t h) {  // low 16 bits -> fp32
    union { uint32_t u; float f; } x; x.u = h << 16; return x.f;
}

// ---------------------------------------------------------------------------
// pack_px: [32][HW] f32 -> [HW][32] bf16. blockIdx.y: 0,1 = x b0,b1; 2,3 = off.
// ---------------------------------------------------------------------------
__global__ __launch_bounds__(256) void pack_px(
    const float* __restrict__ x, const float* __restrict__ off,
    uint16_t* __restrict__ xpk, uint16_t* __restrict__ offpk)
{
    const int z = blockIdx.y;
    const float* src = (z < 2) ? (x + (size_t)z * CH * HW)
                               : (off + (size_t)(z - 2) * CH * HW);
    uint16_t* dst = (z < 2) ? (xpk + (size_t)z * HW * CH)
                            : (offpk + (size_t)(z - 2) * HW * CH);
    const int px = blockIdx.x * 256 + threadIdx.x;
    uint32_t w[16];
    #pragma unroll
    for (int c = 0; c < CH; c += 2) {
        const float a = src[(size_t)c * HW + px];
        const float b = src[(size_t)(c + 1) * HW + px];
        w[c >> 1] = (uint32_t)f2bf(a) | ((uint32_t)f2bf(b) << 16);
    }
    u32x4* d = (u32x4*)(dst + (size_t)px * CH);
    #pragma unroll
    for (int i = 0; i < 4; i++) {
        u32x4 v = { w[4 * i], w[4 * i + 1], w[4 * i + 2], w[4 * i + 3] };
        d[i] = v;
    }
}

// ---------------------------------------------------------------------------
// pack_w: weight repacks. Inputs OIHW, t = kh*3+kw.
// ---------------------------------------------------------------------------
__global__ __launch_bounds__(256) void pack_w(
    const float* __restrict__ w_off, const float* __restrict__ w_c1,
    const float* __restrict__ w_dcn,
    uint16_t* __restrict__ wpk_off, uint16_t* __restrict__ wpk_c1,
    float* __restrict__ wt_dcn)
{
    const int i = blockIdx.x * 256 + threadIdx.x;
    if (i < WPK_OFF_N) {
        const int ic = i & 31, r = (i >> 5) & 15, mt = (i >> 9) & 15, t = i >> 13;
        const int oc = mt * 16 + r;
        const float v = (oc < OMC) ? w_off[((size_t)oc * CH + ic) * 9 + t] : 0.f;
        wpk_off[i] = f2bf(v);
    } else if (i < WPK_OFF_N + WPK_C1_N) {
        const int j = i - WPK_OFF_N;
        const int ic = j & 31, r = (j >> 5) & 15, mt = (j >> 9) & 1, t = j >> 10;
        const int oc = mt * 16 + r;
        wpk_c1[j] = f2bf(w_c1[((size_t)oc * CH + ic) * 9 + t]);
    } else if (i < WPK_OFF_N + WPK_C1_N + WTDCN_N) {
        const int j = i - (WPK_OFF_N + WPK_C1_N);
        const int o = j & 31, row = j >> 5;          // row = ic*9 + k
        wt_dcn[j] = w_dcn[(size_t)o * 288 + row];
    }
}

// ---------------------------------------------------------------------------
// conv_off_mfma: block = 4 rows x 16 cols output, all 256 (padded) oc.
// ---------------------------------------------------------------------------
__global__ __launch_bounds__(256) void conv_off_mfma(
    const uint16_t* __restrict__ inpk,  // [HW][32] bf16 (offset, batch base)
    const uint16_t* __restrict__ wpk,   // [9][16][16][32] bf16
    const float* __restrict__ bias,     // [216]
    float* __restrict__ om,             // [216][rows][256] f32
    int r0, int rows)
{
    __shared__ __align__(16) uint16_t tile[6 * 18 * 40];  // 8640 B

    const int gy0 = r0 + blockIdx.y * 4 - 1;
    const int gx0 = blockIdx.x * 16 - 1;
    for (int chunk = threadIdx.x; chunk < 6 * 18 * 4; chunk += 256) {
        const int rec = chunk >> 2, part = chunk & 3;
        const int rr = rec / 18, rc = rec - rr * 18;
        const int gy = gy0 + rr, gx = gx0 + rc;
        u32x4 v = {0u, 0u, 0u, 0u};
        if ((unsigned)gy < (unsigned)HH && (unsigned)gx < (unsigned)WW)
            v = *(const u32x4*)(inpk + ((size_t)gy * WW + gx) * CH + part * 8);
        *(u32x4*)((char*)tile + rec * 80 + part * 16) = v;
    }
    __syncthreads();

    const int lane = threadIdx.x & 63;
    const int wave = threadIdx.x >> 6;
    const int tx = lane & 15;
    const int q  = lane >> 4;

    f32x4 acc[4][4];
    #pragma unroll
    for (int m = 0; m < 4; m++)
        #pragma unroll
        for (int n = 0; n < 4; n++) acc[m][n] = (f32x4){0.f, 0.f, 0.f, 0.f};

    #pragma unroll
    for (int t = 0; t < 9; t++) {
        const int kh = t / 3, kw = t - kh * 3;
        short8 bfr[4], afr[4];
        #pragma unroll
        for (int n = 0; n < 4; n++)
            bfr[n] = *(const short8*)((const char*)tile +
                       ((n + kh) * 18 + (tx + kw)) * 80 + q * 16);
        #pragma unroll
        for (int m = 0; m < 4; m++) {
            const int mt = wave * 4 + m;
            afr[m] = *(const short8*)(wpk +
                       (((size_t)t * 16 + mt) * 16 + tx) * 32 + q * 8);
        }
        #pragma unroll
        for (int m = 0; m < 4; m++)
            #pragma unroll
            for (int n = 0; n < 4; n++)
                acc[m][n] = __builtin_amdgcn_mfma_f32_16x16x32_bf16(
                    afr[m], bfr[n], acc[m][n], 0, 0, 0);
    }

    const int srW = rows * WW;
    const int gx = blockIdx.x * 16 + tx;
    #pragma unroll
    for (int m = 0; m < 4; m++) {
        const int mt = wave * 4 + m;
        #pragma unroll
        for (int n = 0; n < 4; n++) {
            const int hr = blockIdx.y * 4 + n;
            #pragma unroll
            for (int i = 0; i < 4; i++) {
                const int oc = mt * 16 + q * 4 + i;
                if (oc < OMC)
                    om[(size_t)oc * srW + hr * WW + gx] = acc[m][n][i] + bias[oc];
            }
        }
    }
}

// ---------------------------------------------------------------------------
// conv_c1_mfma: block = 8 rows x 16 cols, M=32 (2 m-tiles). Fused bias+resid.
// ---------------------------------------------------------------------------
__global__ __launch_bounds__(256) void conv_c1_mfma(
    const uint16_t* __restrict__ feapk, // [HW][32] bf16 batch base
    const uint16_t* __restrict__ wpk,   // [9][2][16][32] bf16
    const float* __restrict__ bias,     // [32]
    const float* __restrict__ resid,    // [32][HW] f32 batch base (x)
    float* __restrict__ out)            // [32][HW] f32 batch base
{
    __shared__ __align__(16) uint16_t tile[10 * 18 * 40];  // 14400 B

    const int gy0 = blockIdx.y * 8 - 1;
    const int gx0 = blockIdx.x * 16 - 1;
    for (int chunk = threadIdx.x; chunk < 10 * 18 * 4; chunk += 256) {
        const int rec = chunk >> 2, part = chunk & 3;
        const int rr = rec / 18, rc = rec - rr * 18;
        const int gy = gy0 + rr, gx = gx0 + rc;
        u32x4 v = {0u, 0u, 0u, 0u};
        if ((unsigned)gy < (unsigned)HH && (unsigned)gx < (unsigned)WW)
            v = *(const u32x4*)(feapk + ((size_t)gy * WW + gx) * CH + part * 8);
        *(u32x4*)((char*)tile + rec * 80 + part * 16) = v;
    }
    __syncthreads();

    const int lane = threadIdx.x & 63;
    const int wave = threadIdx.x >> 6;
    const int tx = lane & 15;
    const int q  = lane >> 4;
    const int mt = wave & 1;
    const int nb = (wave >> 1) * 4;

    f32x4 acc[4];
    #pragma unroll
    for (int n = 0; n < 4; n++) acc[n] = (f32x4){0.f, 0.f, 0.f, 0.f};

    #pragma unroll
    for (int t = 0; t < 9; t++) {
        const int kh = t / 3, kw = t - kh * 3;
        const short8 afr = *(const short8*)(wpk +
                             (((size_t)t * 2 + mt) * 16 + tx) * 32 + q * 8);
        #pragma unroll
        for (int n = 0; n < 4; n++) {
            const short8 bfr = *(const short8*)((const char*)tile +
                                 ((nb + n + kh) * 18 + (tx + kw)) * 80 + q * 16);
            acc[n] = __builtin_amdgcn_mfma_f32_16x16x32_bf16(
                afr, bfr, acc[n], 0, 0, 0);
        }
    }

    const int gx = blockIdx.x * 16 + tx;
    #pragma unroll
    for (int n = 0; n < 4; n++) {
        const int gy = blockIdx.y * 8 + nb + n;
        #pragma unroll
        for (int i = 0; i < 4; i++) {
            const int oc = mt * 16 + q * 4 + i;
            const size_t idx = (size_t)oc * HW + (size_t)gy * WW + gx;
            out[idx] = acc[n][i] + bias[oc] + resid[idx];
        }
    }
}

// ---------------------------------------------------------------------------
// dcn_kernel v4: 8 sub-threads per pixel (1 deformable group each);
// wave = 8 px x 8 subs; acc[32] reduced via shfl_xor(8,16,32).
// Grid: rows*8 blocks of 256 (32 px/block) -> 8192 waves/launch.
// launch_bounds (256,6): 85-VGPR budget — no spill (r8's (256,8) spilled).
// ---------------------------------------------------------------------------
__global__ __launch_bounds__(256, 6) void dcn_kernel(
    const uint16_t* __restrict__ xpk,   // [HW][32] bf16 batch base
    const float* __restrict__ om,       // [216][rows][256] f32
    const float* __restrict__ wt,       // [288][32] f32, row = ic*9+k
    const float* __restrict__ b_dcn,    // [32]
    uint16_t* __restrict__ feapk,       // [HW][32] bf16 batch base
    int r0, int rows)
{
    const int lane = threadIdx.x & 63;
    const int wave = threadIdx.x >> 6;
    const int g    = lane >> 3;                 // sub = deformable group 0..7
    const int p    = blockIdx.x * 32 + (wave << 3) + (lane & 7);
    const int hr = p >> 8;
    const int wx = p & 255;
    const int h  = r0 + hr;
    const int srW = rows * WW;

    float acc[CH];
    #pragma unroll
    for (int o = 0; o < CH; o++) acc[o] = 0.f;

    #pragma unroll 3
    for (int k = 0; k < 9; k++) {
        const int ch = g * 9 + k;
        const float dy = om[(size_t)ch * srW + p];
        const float dx = om[(size_t)(72 + ch) * srW + p];
        const float mm = om[(size_t)(144 + ch) * srW + p];
        const float mask = 1.f / (1.f + __expf(-mm));

        const float py = dy + (float)(h + k / 3 - 1);
        const float px = dx + (float)(wx + k % 3 - 1);
        const float y0f = floorf(py), x0f = floorf(px);
        const int y0 = (int)y0f, x0 = (int)x0f;
        const float ly = py - y0f, lx = px - x0f;

        float w00 = (1.f - ly) * (1.f - lx), w01 = (1.f - ly) * lx;
        float w10 = ly * (1.f - lx),         w11 = ly * lx;
        if (!((unsigned)y0       < (unsigned)HH && (unsigned)x0       < (unsigned)WW)) w00 = 0.f;
        if (!((unsigned)y0       < (unsigned)HH && (unsigned)(x0 + 1) < (unsigned)WW)) w01 = 0.f;
        if (!((unsigned)(y0 + 1) < (unsigned)HH && (unsigned)x0       < (unsigned)WW)) w10 = 0.f;
        if (!((unsigned)(y0 + 1) < (unsigned)HH && (unsigned)(x0 + 1) < (unsigned)WW)) w11 = 0.f;
        w00 *= mask; w01 *= mask; w10 *= mask; w11 *= mask;

        const int cy0 = min(max(y0, 0), HH - 1), cy1 = min(max(y0 + 1, 0), HH - 1);
        const int cx0 = min(max(x0, 0), WW - 1), cx1 = min(max(x0 + 1, 0), WW - 1);

        const u32x2 v00 = *(const u32x2*)(xpk + ((size_t)cy0 * WW + cx0) * CH + g * 4);
        const u32x2 v01 = *(const u32x2*)(xpk + ((size_t)cy0 * WW + cx1) * CH + g * 4);
        const u32x2 v10 = *(const u32x2*)(xpk + ((size_t)cy1 * WW + cx0) * CH + g * 4);
        const u32x2 v11 = *(const u32x2*)(xpk + ((size_t)cy1 * WW + cx1) * CH + g * 4);

        #pragma unroll
        for (int c = 0; c < 4; c++) {
            const int sh = (c & 1) * 16;
            const int wi = c >> 1;
            const float f00 = bf2f((v00[wi] >> sh) & 0xffffu);
            const float f01 = bf2f((v01[wi] >> sh) & 0xffffu);
            const float f10 = bf2f((v10[wi] >> sh) & 0xffffu);
            const float f11 = bf2f((v11[wi] >> sh) & 0xffffu);
            const float v = w00 * f00 + w01 * f01 + w10 * f10 + w11 * f11;
            const float* wrow = wt + (size_t)((g * 4 + c) * 9 + k) * CH;
            #pragma unroll
            for (int o = 0; o < CH; o++)
                acc[o] = fmaf(wrow[o], v, acc[o]);
        }
    }

    // reduce partial acc across the 8 subs (lanes ^8, ^16, ^32)
    #pragma unroll
    for (int o = 0; o < CH; o++) {
        acc[o] += __shfl_xor(acc[o], 8, 64);
        acc[o] += __shfl_xor(acc[o], 16, 64);
        acc[o] += __shfl_xor(acc[o], 32, 64);
    }

    if (g == 0) {
        uint32_t wout[16];
        #pragma unroll
        for (int o = 0; o < CH; o += 2) {
            float v0 = acc[o] + b_dcn[o];         v0 = v0 > 0.f ? v0 : NEG_SLOPE * v0;
            float v1 = acc[o + 1] + b_dcn[o + 1]; v1 = v1 > 0.f ? v1 : NEG_SLOPE * v1;
            wout[o >> 1] = (uint32_t)f2bf(v0) | ((uint32_t)f2bf(v1) << 16);
        }
        u32x4* d = (u32x4*)(feapk + ((size_t)h * WW + wx) * CH);
        #pragma unroll
        for (int i = 0; i < 4; i++) {
            u32x4 v = { wout[4 * i], wout[4 * i + 1], wout[4 * i + 2], wout[4 * i + 3] };
            d[i] = v;
        }
    }
}

extern "C" void kernel_launch(void* const* d_in, const int* in_sizes, int n_in,
                              void* d_out, int out_size, void* d_ws, size_t ws_size,
                              hipStream_t stream) {
    const float* x      = (const float*)d_in[0];
    const float* offset = (const float*)d_in[1];
    const float* w_off  = (const float*)d_in[2];
    const float* b_off  = (const float*)d_in[3];
    const float* w_dcn  = (const float*)d_in[4];
    const float* b_dcn  = (const float*)d_in[5];
    const float* w_c1   = (const float*)d_in[6];
    const float* b_c1   = (const float*)d_in[7];
    float* out = (float*)d_out;

    auto aup = [](size_t v) { return (v + 255) & ~(size_t)255; };
    char* wsp = (char*)d_ws;
    uint16_t* xpk    = (uint16_t*)wsp; wsp += aup((size_t)BB * HW * CH * 2);
    uint16_t* offpk  = (uint16_t*)wsp; wsp += aup((size_t)BB * HW * CH * 2);
    uint16_t* feapk  = (uint16_t*)wsp; wsp += aup((size_t)BB * HW * CH * 2);
    uint16_t* wpkoff = (uint16_t*)wsp; wsp += aup((size_t)WPK_OFF_N * 2);
    uint16_t* wpkc1  = (uint16_t*)wsp; wsp += aup((size_t)WPK_C1_N * 2);
    float*    wtdcn  = (float*)wsp;    wsp += aup((size_t)WTDCN_N * 4);
    float*    om     = (float*)wsp;
    const size_t used = (size_t)(wsp - (char*)d_ws);

    const size_t row_bytes = (size_t)OMC * WW * sizeof(float);  // 221184
    const size_t avail = (ws_size > used) ? (ws_size - used) : 0;
    int rows_per = (int)(avail / row_bytes) & ~3;   // multiple of 4
    if (rows_per < 4)  rows_per = 4;
    if (rows_per > HH) rows_per = HH;

    // 0) packs
    pack_px<<<dim3(HW / 256, 4), dim3(256), 0, stream>>>(x, offset, xpk, offpk);
    const int wn = WPK_OFF_N + WPK_C1_N + WTDCN_N;
    pack_w<<<dim3((wn + 255) / 256), dim3(256), 0, stream>>>(
        w_off, w_c1, w_dcn, wpkoff, wpkc1, wtdcn);

    // 1+2) per batch, per row-stripe: conv_off (MFMA) -> om, dcn -> feapk
    for (int b = 0; b < BB; b++) {
        const uint16_t* offb = offpk + (size_t)b * HW * CH;
        const uint16_t* xb   = xpk   + (size_t)b * HW * CH;
        uint16_t*       feab = feapk + (size_t)b * HW * CH;
        for (int r0 = 0; r0 < HH; r0 += rows_per) {
            const int rows = (r0 + rows_per <= HH) ? rows_per : (HH - r0);
            conv_off_mfma<<<dim3(WW / 16, rows / 4), dim3(256), 0, stream>>>(
                offb, wpkoff, b_off, om, r0, rows);
            dcn_kernel<<<dim3(rows * 8), dim3(256), 0, stream>>>(
                xb, om, wtdcn, b_dcn, feab, r0, rows);
        }
    }

    // 3) conv c1 (MFMA) + bias + residual
    for (int b = 0; b < BB; b++) {
        conv_c1_mfma<<<dim3(WW / 16, HH / 8), dim3(256), 0, stream>>>(
            feapk + (size_t)b * HW * CH, wpkc1, b_c1,
            x + (size_t)b * CH * HW, out + (size_t)b * CH * HW);
    }
}

// Round 12
// 381.898 us; speedup vs baseline: 1.5981x; 1.2473x over previous
//
#include <hip/hip_runtime.h>
#include <cstddef>
#include <cstdint>

// RSABlock: conv_offset_mask (3x3) -> DCNv2 -> leaky_relu -> conv3x3 -> +x.
// B=2, C=32, H=W=256, DG=8, K=9, om channels = 216.
//
// Round 12 (= round 10/11 resubmitted; infra timeouts): dcn 8 subs/pixel with
// __launch_bounds__(256,4). Empirical: compiler budgets 256/wavesPerEU
// arch-VGPRs ((256,6)->40, (256,8)->32 -> acc[32] spills; (256,4)->64 fits).
// Grid 8192 waves + ~56 VGPR -> hardware allows 8 waves/SIMD: occupancy
// without spill.

#define CH 32
#define HH 256
#define WW 256
#define BB 2
#define HW (HH * WW)
#define OMC 216
#define NEG_SLOPE 0.2f

typedef __attribute__((ext_vector_type(8))) short short8;
typedef __attribute__((ext_vector_type(4))) float f32x4;
typedef __attribute__((ext_vector_type(4))) unsigned int u32x4;
typedef __attribute__((ext_vector_type(2))) unsigned int u32x2;

#define WPK_OFF_N (9 * 16 * 16 * 32)  // 73728
#define WPK_C1_N  (9 * 2 * 16 * 32)   // 9216
#define WTDCN_N   (288 * 32)          // 9216

__device__ __forceinline__ uint16_t f2bf(float f) {  // RNE fp32->bf16
    union { float f; uint32_t u; } x; x.f = f;
    const uint32_t r = x.u + 0x7fffu + ((x.u >> 16) & 1u);
    return (uint16_t)(r >> 16);
}
__device__ __forceinline__ float bf2f(uint32_t h) {  // low 16 bits -> fp32
    union { uint32_t u; float f; } x; x.u = h << 16; return x.f;
}

// ---------------------------------------------------------------------------
// pack_px: [32][HW] f32 -> [HW][32] bf16. blockIdx.y: 0,1 = x b0,b1; 2,3 = off.
// ---------------------------------------------------------------------------
__global__ __launch_bounds__(256) void pack_px(
    const float* __restrict__ x, const float* __restrict__ off,
    uint16_t* __restrict__ xpk, uint16_t* __restrict__ offpk)
{
    const int z = blockIdx.y;
    const float* src = (z < 2) ? (x + (size_t)z * CH * HW)
                               : (off + (size_t)(z - 2) * CH * HW);
    uint16_t* dst = (z < 2) ? (xpk + (size_t)z * HW * CH)
                            : (offpk + (size_t)(z - 2) * HW * CH);
    const int px = blockIdx.x * 256 + threadIdx.x;
    uint32_t w[16];
    #pragma unroll
    for (int c = 0; c < CH; c += 2) {
        const float a = src[(size_t)c * HW + px];
        const float b = src[(size_t)(c + 1) * HW + px];
        w[c >> 1] = (uint32_t)f2bf(a) | ((uint32_t)f2bf(b) << 16);
    }
    u32x4* d = (u32x4*)(dst + (size_t)px * CH);
    #pragma unroll
    for (int i = 0; i < 4; i++) {
        u32x4 v = { w[4 * i], w[4 * i + 1], w[4 * i + 2], w[4 * i + 3] };
        d[i] = v;
    }
}

// ---------------------------------------------------------------------------
// pack_w: weight repacks. Inputs OIHW, t = kh*3+kw.
// ---------------------------------------------------------------------------
__global__ __launch_bounds__(256) void pack_w(
    const float* __restrict__ w_off, const float* __restrict__ w_c1,
    const float* __restrict__ w_dcn,
    uint16_t* __restrict__ wpk_off, uint16_t* __restrict__ wpk_c1,
    float* __restrict__ wt_dcn)
{
    const int i = blockIdx.x * 256 + threadIdx.x;
    if (i < WPK_OFF_N) {
        const int ic = i & 31, r = (i >> 5) & 15, mt = (i >> 9) & 15, t = i >> 13;
        const int oc = mt * 16 + r;
        const float v = (oc < OMC) ? w_off[((size_t)oc * CH + ic) * 9 + t] : 0.f;
        wpk_off[i] = f2bf(v);
    } else if (i < WPK_OFF_N + WPK_C1_N) {
        const int j = i - WPK_OFF_N;
        const int ic = j & 31, r = (j >> 5) & 15, mt = (j >> 9) & 1, t = j >> 10;
        const int oc = mt * 16 + r;
        wpk_c1[j] = f2bf(w_c1[((size_t)oc * CH + ic) * 9 + t]);
    } else if (i < WPK_OFF_N + WPK_C1_N + WTDCN_N) {
        const int j = i - (WPK_OFF_N + WPK_C1_N);
        const int o = j & 31, row = j >> 5;          // row = ic*9 + k
        wt_dcn[j] = w_dcn[(size_t)o * 288 + row];
    }
}

// ---------------------------------------------------------------------------
// conv_off_mfma: block = 4 rows x 16 cols output, all 256 (padded) oc.
// ---------------------------------------------------------------------------
__global__ __launch_bounds__(256) void conv_off_mfma(
    const uint16_t* __restrict__ inpk,  // [HW][32] bf16 (offset, batch base)
    const uint16_t* __restrict__ wpk,   // [9][16][16][32] bf16
    const float* __restrict__ bias,     // [216]
    float* __restrict__ om,             // [216][rows][256] f32
    int r0, int rows)
{
    __shared__ __align__(16) uint16_t tile[6 * 18 * 40];  // 8640 B

    const int gy0 = r0 + blockIdx.y * 4 - 1;
    const int gx0 = blockIdx.x * 16 - 1;
    for (int chunk = threadIdx.x; chunk < 6 * 18 * 4; chunk += 256) {
        const int rec = chunk >> 2, part = chunk & 3;
        const int rr = rec / 18, rc = rec - rr * 18;
        const int gy = gy0 + rr, gx = gx0 + rc;
        u32x4 v = {0u, 0u, 0u, 0u};
        if ((unsigned)gy < (unsigned)HH && (unsigned)gx < (unsigned)WW)
            v = *(const u32x4*)(inpk + ((size_t)gy * WW + gx) * CH + part * 8);
        *(u32x4*)((char*)tile + rec * 80 + part * 16) = v;
    }
    __syncthreads();

    const int lane = threadIdx.x & 63;
    const int wave = threadIdx.x >> 6;
    const int tx = lane & 15;
    const int q  = lane >> 4;

    f32x4 acc[4][4];
    #pragma unroll
    for (int m = 0; m < 4; m++)
        #pragma unroll
        for (int n = 0; n < 4; n++) acc[m][n] = (f32x4){0.f, 0.f, 0.f, 0.f};

    #pragma unroll
    for (int t = 0; t < 9; t++) {
        const int kh = t / 3, kw = t - kh * 3;
        short8 bfr[4], afr[4];
        #pragma unroll
        for (int n = 0; n < 4; n++)
            bfr[n] = *(const short8*)((const char*)tile +
                       ((n + kh) * 18 + (tx + kw)) * 80 + q * 16);
        #pragma unroll
        for (int m = 0; m < 4; m++) {
            const int mt = wave * 4 + m;
            afr[m] = *(const short8*)(wpk +
                       (((size_t)t * 16 + mt) * 16 + tx) * 32 + q * 8);
        }
        #pragma unroll
        for (int m = 0; m < 4; m++)
            #pragma unroll
            for (int n = 0; n < 4; n++)
                acc[m][n] = __builtin_amdgcn_mfma_f32_16x16x32_bf16(
                    afr[m], bfr[n], acc[m][n], 0, 0, 0);
    }

    const int srW = rows * WW;
    const int gx = blockIdx.x * 16 + tx;
    #pragma unroll
    for (int m = 0; m < 4; m++) {
        const int mt = wave * 4 + m;
        #pragma unroll
        for (int n = 0; n < 4; n++) {
            const int hr = blockIdx.y * 4 + n;
            #pragma unroll
            for (int i = 0; i < 4; i++) {
                const int oc = mt * 16 + q * 4 + i;
                if (oc < OMC)
                    om[(size_t)oc * srW + hr * WW + gx] = acc[m][n][i] + bias[oc];
            }
        }
    }
}

// ---------------------------------------------------------------------------
// conv_c1_mfma: block = 8 rows x 16 cols, M=32 (2 m-tiles). Fused bias+resid.
// ---------------------------------------------------------------------------
__global__ __launch_bounds__(256) void conv_c1_mfma(
    const uint16_t* __restrict__ feapk, // [HW][32] bf16 batch base
    const uint16_t* __restrict__ wpk,   // [9][2][16][32] bf16
    const float* __restrict__ bias,     // [32]
    const float* __restrict__ resid,    // [32][HW] f32 batch base (x)
    float* __restrict__ out)            // [32][HW] f32 batch base
{
    __shared__ __align__(16) uint16_t tile[10 * 18 * 40];  // 14400 B

    const int gy0 = blockIdx.y * 8 - 1;
    const int gx0 = blockIdx.x * 16 - 1;
    for (int chunk = threadIdx.x; chunk < 10 * 18 * 4; chunk += 256) {
        const int rec = chunk >> 2, part = chunk & 3;
        const int rr = rec / 18, rc = rec - rr * 18;
        const int gy = gy0 + rr, gx = gx0 + rc;
        u32x4 v = {0u, 0u, 0u, 0u};
        if ((unsigned)gy < (unsigned)HH && (unsigned)gx < (unsigned)WW)
            v = *(const u32x4*)(feapk + ((size_t)gy * WW + gx) * CH + part * 8);
        *(u32x4*)((char*)tile + rec * 80 + part * 16) = v;
    }
    __syncthreads();

    const int lane = threadIdx.x & 63;
    const int wave = threadIdx.x >> 6;
    const int tx = lane & 15;
    const int q  = lane >> 4;
    const int mt = wave & 1;
    const int nb = (wave >> 1) * 4;

    f32x4 acc[4];
    #pragma unroll
    for (int n = 0; n < 4; n++) acc[n] = (f32x4){0.f, 0.f, 0.f, 0.f};

    #pragma unroll
    for (int t = 0; t < 9; t++) {
        const int kh = t / 3, kw = t - kh * 3;
        const short8 afr = *(const short8*)(wpk +
                             (((size_t)t * 2 + mt) * 16 + tx) * 32 + q * 8);
        #pragma unroll
        for (int n = 0; n < 4; n++) {
            const short8 bfr = *(const short8*)((const char*)tile +
                                 ((nb + n + kh) * 18 + (tx + kw)) * 80 + q * 16);
            acc[n] = __builtin_amdgcn_mfma_f32_16x16x32_bf16(
                afr, bfr, acc[n], 0, 0, 0);
        }
    }

    const int gx = blockIdx.x * 16 + tx;
    #pragma unroll
    for (int n = 0; n < 4; n++) {
        const int gy = blockIdx.y * 8 + nb + n;
        #pragma unroll
        for (int i = 0; i < 4; i++) {
            const int oc = mt * 16 + q * 4 + i;
            const size_t idx = (size_t)oc * HW + (size_t)gy * WW + gx;
            out[idx] = acc[n][i] + bias[oc] + resid[idx];
        }
    }
}

// ---------------------------------------------------------------------------
// dcn_kernel v5: 8 sub-threads per pixel (1 deformable group each);
// wave = 8 px x 8 subs; acc[32] reduced via shfl_xor(8,16,32).
// Grid: rows*8 blocks of 256 (32 px/block) -> 8192 waves/launch.
// launch_bounds (256,4): 64-arch-VGPR budget fits acc+working (no spill);
// hardware still admits ~8 waves/SIMD at this VGPR count.
// ---------------------------------------------------------------------------
__global__ __launch_bounds__(256, 4) void dcn_kernel(
    const uint16_t* __restrict__ xpk,   // [HW][32] bf16 batch base
    const float* __restrict__ om,       // [216][rows][256] f32
    const float* __restrict__ wt,       // [288][32] f32, row = ic*9+k
    const float* __restrict__ b_dcn,    // [32]
    uint16_t* __restrict__ feapk,       // [HW][32] bf16 batch base
    int r0, int rows)
{
    const int lane = threadIdx.x & 63;
    const int wave = threadIdx.x >> 6;
    const int g    = lane >> 3;                 // sub = deformable group 0..7
    const int p    = blockIdx.x * 32 + (wave << 3) + (lane & 7);
    const int hr = p >> 8;
    const int wx = p & 255;
    const int h  = r0 + hr;
    const int srW = rows * WW;

    float acc[CH];
    #pragma unroll
    for (int o = 0; o < CH; o++) acc[o] = 0.f;

    #pragma unroll 3
    for (int k = 0; k < 9; k++) {
        const int ch = g * 9 + k;
        const float dy = om[(size_t)ch * srW + p];
        const float dx = om[(size_t)(72 + ch) * srW + p];
        const float mm = om[(size_t)(144 + ch) * srW + p];
        const float mask = 1.f / (1.f + __expf(-mm));

        const float py = dy + (float)(h + k / 3 - 1);
        const float px = dx + (float)(wx + k % 3 - 1);
        const float y0f = floorf(py), x0f = floorf(px);
        const int y0 = (int)y0f, x0 = (int)x0f;
        const float ly = py - y0f, lx = px - x0f;

        float w00 = (1.f - ly) * (1.f - lx), w01 = (1.f - ly) * lx;
        float w10 = ly * (1.f - lx),         w11 = ly * lx;
        if (!((unsigned)y0       < (unsigned)HH && (unsigned)x0       < (unsigned)WW)) w00 = 0.f;
        if (!((unsigned)y0       < (unsigned)HH && (unsigned)(x0 + 1) < (unsigned)WW)) w01 = 0.f;
        if (!((unsigned)(y0 + 1) < (unsigned)HH && (unsigned)x0       < (unsigned)WW)) w10 = 0.f;
        if (!((unsigned)(y0 + 1) < (unsigned)HH && (unsigned)(x0 + 1) < (unsigned)WW)) w11 = 0.f;
        w00 *= mask; w01 *= mask; w10 *= mask; w11 *= mask;

        const int cy0 = min(max(y0, 0), HH - 1), cy1 = min(max(y0 + 1, 0), HH - 1);
        const int cx0 = min(max(x0, 0), WW - 1), cx1 = min(max(x0 + 1, 0), WW - 1);

        const u32x2 v00 = *(const u32x2*)(xpk + ((size_t)cy0 * WW + cx0) * CH + g * 4);
        const u32x2 v01 = *(const u32x2*)(xpk + ((size_t)cy0 * WW + cx1) * CH + g * 4);
        const u32x2 v10 = *(const u32x2*)(xpk + ((size_t)cy1 * WW + cx0) * CH + g * 4);
        const u32x2 v11 = *(const u32x2*)(xpk + ((size_t)cy1 * WW + cx1) * CH + g * 4);

        #pragma unroll
        for (int c = 0; c < 4; c++) {
            const int sh = (c & 1) * 16;
            const int wi = c >> 1;
            const float f00 = bf2f((v00[wi] >> sh) & 0xffffu);
            const float f01 = bf2f((v01[wi] >> sh) & 0xffffu);
            const float f10 = bf2f((v10[wi] >> sh) & 0xffffu);
            const float f11 = bf2f((v11[wi] >> sh) & 0xffffu);
            const float v = w00 * f00 + w01 * f01 + w10 * f10 + w11 * f11;
            const float* wrow = wt + (size_t)((g * 4 + c) * 9 + k) * CH;
            #pragma unroll
            for (int o = 0; o < CH; o++)
                acc[o] = fmaf(wrow[o], v, acc[o]);
        }
    }

    // reduce partial acc across the 8 subs (lanes ^8, ^16, ^32)
    #pragma unroll
    for (int o = 0; o < CH; o++) {
        acc[o] += __shfl_xor(acc[o], 8, 64);
        acc[o] += __shfl_xor(acc[o], 16, 64);
        acc[o] += __shfl_xor(acc[o], 32, 64);
    }

    if (g == 0) {
        uint32_t wout[16];
        #pragma unroll
        for (int o = 0; o < CH; o += 2) {
            float v0 = acc[o] + b_dcn[o];         v0 = v0 > 0.f ? v0 : NEG_SLOPE * v0;
            float v1 = acc[o + 1] + b_dcn[o + 1]; v1 = v1 > 0.f ? v1 : NEG_SLOPE * v1;
            wout[o >> 1] = (uint32_t)f2bf(v0) | ((uint32_t)f2bf(v1) << 16);
        }
        u32x4* d = (u32x4*)(feapk + ((size_t)h * WW + wx) * CH);
        #pragma unroll
        for (int i = 0; i < 4; i++) {
            u32x4 v = { wout[4 * i], wout[4 * i + 1], wout[4 * i + 2], wout[4 * i + 3] };
            d[i] = v;
        }
    }
}

extern "C" void kernel_launch(void* const* d_in, const int* in_sizes, int n_in,
                              void* d_out, int out_size, void* d_ws, size_t ws_size,
                              hipStream_t stream) {
    const float* x      = (const float*)d_in[0];
    const float* offset = (const float*)d_in[1];
    const float* w_off  = (const float*)d_in[2];
    const float* b_off  = (const float*)d_in[3];
    const float* w_dcn  = (const float*)d_in[4];
    const float* b_dcn  = (const float*)d_in[5];
    const float* w_c1   = (const float*)d_in[6];
    const float* b_c1   = (const float*)d_in[7];
    float* out = (float*)d_out;

    auto aup = [](size_t v) { return (v + 255) & ~(size_t)255; };
    char* wsp = (char*)d_ws;
    uint16_t* xpk    = (uint16_t*)wsp; wsp += aup((size_t)BB * HW * CH * 2);
    uint16_t* offpk  = (uint16_t*)wsp; wsp += aup((size_t)BB * HW * CH * 2);
    uint16_t* feapk  = (uint16_t*)wsp; wsp += aup((size_t)BB * HW * CH * 2);
    uint16_t* wpkoff = (uint16_t*)wsp; wsp += aup((size_t)WPK_OFF_N * 2);
    uint16_t* wpkc1  = (uint16_t*)wsp; wsp += aup((size_t)WPK_C1_N * 2);
    float*    wtdcn  = (float*)wsp;    wsp += aup((size_t)WTDCN_N * 4);
    float*    om     = (float*)wsp;
    const size_t used = (size_t)(wsp - (char*)d_ws);

    const size_t row_bytes = (size_t)OMC * WW * sizeof(float);  // 221184
    const size_t avail = (ws_size > used) ? (ws_size - used) : 0;
    int rows_per = (int)(avail / row_bytes) & ~3;   // multiple of 4
    if (rows_per < 4)  rows_per = 4;
    if (rows_per > HH) rows_per = HH;

    // 0) packs
    pack_px<<<dim3(HW / 256, 4), dim3(256), 0, stream>>>(x, offset, xpk, offpk);
    const int wn = WPK_OFF_N + WPK_C1_N + WTDCN_N;
    pack_w<<<dim3((wn + 255) / 256), dim3(256), 0, stream>>>(
        w_off, w_c1, w_dcn, wpkoff, wpkc1, wtdcn);

    // 1+2) per batch, per row-stripe: conv_off (MFMA) -> om, dcn -> feapk
    for (int b = 0; b < BB; b++) {
        const uint16_t* offb = offpk + (size_t)b * HW * CH;
        const uint16_t* xb   = xpk   + (size_t)b * HW * CH;
        uint16_t*       feab = feapk + (size_t)b * HW * CH;
        for (int r0 = 0; r0 < HH; r0 += rows_per) {
            const int rows = (r0 + rows_per <= HH) ? rows_per : (HH - r0);
            conv_off_mfma<<<dim3(WW / 16, rows / 4), dim3(256), 0, stream>>>(
                offb, wpkoff, b_off, om, r0, rows);
            dcn_kernel<<<dim3(rows * 8), dim3(256), 0, stream>>>(
                xb, om, wtdcn, b_dcn, feab, r0, rows);
        }
    }

    // 3) conv c1 (MFMA) + bias + residual
    for (int b = 0; b < BB; b++) {
        conv_c1_mfma<<<dim3(WW / 16, HH / 8), dim3(256), 0, stream>>>(
            feapk + (size_t)b * HW * CH, wpkc1, b_c1,
            x + (size_t)b * CH * HW, out + (size_t)b * CH * HW);
    }
}

// Round 17
// 265.603 us; speedup vs baseline: 2.2978x; 1.4378x over previous
//
#include <hip/hip_runtime.h>
#include <cstddef>
#include <cstdint>

// RSABlock: conv_offset_mask (3x3) -> DCNv2 -> leaky_relu -> conv3x3 -> +x.
// B=2, C=32, H=W=256, DG=8, K=9, om channels = 216.
//
// Round 17 (= round 13..16 resubmitted; infra failures): dcn as LDS-V-tile
// + MFMA contraction.
//   Phase 1: 4 waves x 2 groups compute masked bilinear samples -> bf16
//            V[64px][288k] in LDS (pitch 296, 592B = 37x16B, conflict-light).
//   Phase 2: out[32, 64px] = w_dcn[32,288] x V via mfma_16x16x32_bf16
//            (K order = tap*32 + ic; A packed like conv_c1's weights).
// Rationale: rounds 7/12 showed residency capped ~42% at VGPR=56 regardless
// of grid (4096 vs 8192 waves supplied) and VALUBusy 37% on a 1152-FMA/px
// scalar contraction. MFMA deletes that VALU load and the acc[32] footprint.

#define CH 32
#define HH 256
#define WW 256
#define BB 2
#define HW (HH * WW)
#define OMC 216
#define NEG_SLOPE 0.2f
#define VP 296   // V-tile row pitch in bf16 entries (592 B)

typedef __attribute__((ext_vector_type(8))) short short8;
typedef __attribute__((ext_vector_type(4))) float f32x4;
typedef __attribute__((ext_vector_type(4))) unsigned int u32x4;
typedef __attribute__((ext_vector_type(2))) unsigned int u32x2;

#define WPK_OFF_N (9 * 16 * 16 * 32)  // 73728
#define WPK_C1_N  (9 * 2 * 16 * 32)   // 9216
#define WPK_DCN_N (9 * 2 * 16 * 32)   // 9216

__device__ __forceinline__ uint16_t f2bf(float f) {  // RNE fp32->bf16
    union { float f; uint32_t u; } x; x.f = f;
    const uint32_t r = x.u + 0x7fffu + ((x.u >> 16) & 1u);
    return (uint16_t)(r >> 16);
}
__device__ __forceinline__ float bf2f(uint32_t h) {  // low 16 bits -> fp32
    union { uint32_t u; float f; } x; x.u = h << 16; return x.f;
}

// ---------------------------------------------------------------------------
// pack_px: [32][HW] f32 -> [HW][32] bf16. blockIdx.y: 0,1 = x b0,b1; 2,3 = off.
// ---------------------------------------------------------------------------
__global__ __launch_bounds__(256) void pack_px(
    const float* __restrict__ x, const float* __restrict__ off,
    uint16_t* __restrict__ xpk, uint16_t* __restrict__ offpk)
{
    const int z = blockIdx.y;
    const float* src = (z < 2) ? (x + (size_t)z * CH * HW)
                               : (off + (size_t)(z - 2) * CH * HW);
    uint16_t* dst = (z < 2) ? (xpk + (size_t)z * HW * CH)
                            : (offpk + (size_t)(z - 2) * HW * CH);
    const int px = blockIdx.x * 256 + threadIdx.x;
    uint32_t w[16];
    #pragma unroll
    for (int c = 0; c < CH; c += 2) {
        const float a = src[(size_t)c * HW + px];
        const float b = src[(size_t)(c + 1) * HW + px];
        w[c >> 1] = (uint32_t)f2bf(a) | ((uint32_t)f2bf(b) << 16);
    }
    u32x4* d = (u32x4*)(dst + (size_t)px * CH);
    #pragma unroll
    for (int i = 0; i < 4; i++) {
        u32x4 v = { w[4 * i], w[4 * i + 1], w[4 * i + 2], w[4 * i + 3] };
        d[i] = v;
    }
}

// ---------------------------------------------------------------------------
// pack_w: weight repacks. Inputs OIHW, t = kh*3+kw.
//   wpk_off [9][16][16][32] bf16 (M pad 216->256)
//   wpk_c1  [9][2][16][32] bf16
//   wpk_dcn [9][2][16][32] bf16   (same transform, from w_dcn)
// ---------------------------------------------------------------------------
__global__ __launch_bounds__(256) void pack_w(
    const float* __restrict__ w_off, const float* __restrict__ w_c1,
    const float* __restrict__ w_dcn,
    uint16_t* __restrict__ wpk_off, uint16_t* __restrict__ wpk_c1,
    uint16_t* __restrict__ wpk_dcn)
{
    const int i = blockIdx.x * 256 + threadIdx.x;
    if (i < WPK_OFF_N) {
        const int ic = i & 31, r = (i >> 5) & 15, mt = (i >> 9) & 15, t = i >> 13;
        const int oc = mt * 16 + r;
        const float v = (oc < OMC) ? w_off[((size_t)oc * CH + ic) * 9 + t] : 0.f;
        wpk_off[i] = f2bf(v);
    } else if (i < WPK_OFF_N + WPK_C1_N) {
        const int j = i - WPK_OFF_N;
        const int ic = j & 31, r = (j >> 5) & 15, mt = (j >> 9) & 1, t = j >> 10;
        const int oc = mt * 16 + r;
        wpk_c1[j] = f2bf(w_c1[((size_t)oc * CH + ic) * 9 + t]);
    } else if (i < WPK_OFF_N + WPK_C1_N + WPK_DCN_N) {
        const int j = i - (WPK_OFF_N + WPK_C1_N);
        const int ic = j & 31, r = (j >> 5) & 15, mt = (j >> 9) & 1, t = j >> 10;
        const int oc = mt * 16 + r;
        wpk_dcn[j] = f2bf(w_dcn[((size_t)oc * CH + ic) * 9 + t]);
    }
}

// ---------------------------------------------------------------------------
// conv_off_mfma: block = 4 rows x 16 cols output, all 256 (padded) oc.
// ---------------------------------------------------------------------------
__global__ __launch_bounds__(256) void conv_off_mfma(
    const uint16_t* __restrict__ inpk,  // [HW][32] bf16 (offset, batch base)
    const uint16_t* __restrict__ wpk,   // [9][16][16][32] bf16
    const float* __restrict__ bias,     // [216]
    float* __restrict__ om,             // [216][rows][256] f32
    int r0, int rows)
{
    __shared__ __align__(16) uint16_t tile[6 * 18 * 40];  // 8640 B

    const int gy0 = r0 + blockIdx.y * 4 - 1;
    const int gx0 = blockIdx.x * 16 - 1;
    for (int chunk = threadIdx.x; chunk < 6 * 18 * 4; chunk += 256) {
        const int rec = chunk >> 2, part = chunk & 3;
        const int rr = rec / 18, rc = rec - rr * 18;
        const int gy = gy0 + rr, gx = gx0 + rc;
        u32x4 v = {0u, 0u, 0u, 0u};
        if ((unsigned)gy < (unsigned)HH && (unsigned)gx < (unsigned)WW)
            v = *(const u32x4*)(inpk + ((size_t)gy * WW + gx) * CH + part * 8);
        *(u32x4*)((char*)tile + rec * 80 + part * 16) = v;
    }
    __syncthreads();

    const int lane = threadIdx.x & 63;
    const int wave = threadIdx.x >> 6;
    const int tx = lane & 15;
    const int q  = lane >> 4;

    f32x4 acc[4][4];
    #pragma unroll
    for (int m = 0; m < 4; m++)
        #pragma unroll
        for (int n = 0; n < 4; n++) acc[m][n] = (f32x4){0.f, 0.f, 0.f, 0.f};

    #pragma unroll
    for (int t = 0; t < 9; t++) {
        const int kh = t / 3, kw = t - kh * 3;
        short8 bfr[4], afr[4];
        #pragma unroll
        for (int n = 0; n < 4; n++)
            bfr[n] = *(const short8*)((const char*)tile +
                       ((n + kh) * 18 + (tx + kw)) * 80 + q * 16);
        #pragma unroll
        for (int m = 0; m < 4; m++) {
            const int mt = wave * 4 + m;
            afr[m] = *(const short8*)(wpk +
                       (((size_t)t * 16 + mt) * 16 + tx) * 32 + q * 8);
        }
        #pragma unroll
        for (int m = 0; m < 4; m++)
            #pragma unroll
            for (int n = 0; n < 4; n++)
                acc[m][n] = __builtin_amdgcn_mfma_f32_16x16x32_bf16(
                    afr[m], bfr[n], acc[m][n], 0, 0, 0);
    }

    const int srW = rows * WW;
    const int gx = blockIdx.x * 16 + tx;
    #pragma unroll
    for (int m = 0; m < 4; m++) {
        const int mt = wave * 4 + m;
        #pragma unroll
        for (int n = 0; n < 4; n++) {
            const int hr = blockIdx.y * 4 + n;
            #pragma unroll
            for (int i = 0; i < 4; i++) {
                const int oc = mt * 16 + q * 4 + i;
                if (oc < OMC)
                    om[(size_t)oc * srW + hr * WW + gx] = acc[m][n][i] + bias[oc];
            }
        }
    }
}

// ---------------------------------------------------------------------------
// conv_c1_mfma: block = 8 rows x 16 cols, M=32 (2 m-tiles). Fused bias+resid.
// ---------------------------------------------------------------------------
__global__ __launch_bounds__(256) void conv_c1_mfma(
    const uint16_t* __restrict__ feapk, // [HW][32] bf16 batch base
    const uint16_t* __restrict__ wpk,   // [9][2][16][32] bf16
    const float* __restrict__ bias,     // [32]
    const float* __restrict__ resid,    // [32][HW] f32 batch base (x)
    float* __restrict__ out)            // [32][HW] f32 batch base
{
    __shared__ __align__(16) uint16_t tile[10 * 18 * 40];  // 14400 B

    const int gy0 = blockIdx.y * 8 - 1;
    const int gx0 = blockIdx.x * 16 - 1;
    for (int chunk = threadIdx.x; chunk < 10 * 18 * 4; chunk += 256) {
        const int rec = chunk >> 2, part = chunk & 3;
        const int rr = rec / 18, rc = rec - rr * 18;
        const int gy = gy0 + rr, gx = gx0 + rc;
        u32x4 v = {0u, 0u, 0u, 0u};
        if ((unsigned)gy < (unsigned)HH && (unsigned)gx < (unsigned)WW)
            v = *(const u32x4*)(feapk + ((size_t)gy * WW + gx) * CH + part * 8);
        *(u32x4*)((char*)tile + rec * 80 + part * 16) = v;
    }
    __syncthreads();

    const int lane = threadIdx.x & 63;
    const int wave = threadIdx.x >> 6;
    const int tx = lane & 15;
    const int q  = lane >> 4;
    const int mt = wave & 1;
    const int nb = (wave >> 1) * 4;

    f32x4 acc[4];
    #pragma unroll
    for (int n = 0; n < 4; n++) acc[n] = (f32x4){0.f, 0.f, 0.f, 0.f};

    #pragma unroll
    for (int t = 0; t < 9; t++) {
        const int kh = t / 3, kw = t - kh * 3;
        const short8 afr = *(const short8*)(wpk +
                             (((size_t)t * 2 + mt) * 16 + tx) * 32 + q * 8);
        #pragma unroll
        for (int n = 0; n < 4; n++) {
            const short8 bfr = *(const short8*)((const char*)tile +
                                 ((nb + n + kh) * 18 + (tx + kw)) * 80 + q * 16);
            acc[n] = __builtin_amdgcn_mfma_f32_16x16x32_bf16(
                afr, bfr, acc[n], 0, 0, 0);
        }
    }

    const int gx = blockIdx.x * 16 + tx;
    #pragma unroll
    for (int n = 0; n < 4; n++) {
        const int gy = blockIdx.y * 8 + nb + n;
        #pragma unroll
        for (int i = 0; i < 4; i++) {
            const int oc = mt * 16 + q * 4 + i;
            const size_t idx = (size_t)oc * HW + (size_t)gy * WW + gx;
            out[idx] = acc[n][i] + bias[oc] + resid[idx];
        }
    }
}

// ---------------------------------------------------------------------------
// dcn_mfma: block = 64 contiguous px (one quarter-row), 256 threads = 4 waves.
// Phase 1: wave w computes groups 2w,2w+1: masked bilinear samples -> bf16
//          V[px][tap*32 + g*4 + c] in LDS.
// Phase 2: wave w owns n-tile w (16 px): 9 K-steps x 2 m-tiles of
//          mfma_16x16x32_bf16 with A = wpk_dcn[s][mt][row][ic].
// Epilogue: +bias, leaky-relu, pack bf16 -> feapk[px][32] (8B stores).
// ---------------------------------------------------------------------------
__global__ __launch_bounds__(256, 4) void dcn_mfma(
    const uint16_t* __restrict__ xpk,   // [HW][32] bf16 batch base
    const float* __restrict__ om,       // [216][rows][256] f32 (stripe)
    const uint16_t* __restrict__ wpk,   // [9][2][16][32] bf16 (w_dcn)
    const float* __restrict__ b_dcn,    // [32]
    uint16_t* __restrict__ feapk,       // [HW][32] bf16 batch base
    int r0, int rows)
{
    __shared__ __align__(16) uint16_t V[64 * VP];  // 37888 B

    const int tid  = threadIdx.x;
    const int tpx  = tid & 63;          // px within block (== lane)
    const int slot = tid >> 6;          // wave 0..3 -> groups 2s, 2s+1
    const int px0  = blockIdx.x * 64;   // stripe-local base pixel
    const int h    = r0 + (px0 >> 8);   // global row (uniform in block)
    const int wx   = (px0 & 255) + tpx; // global col
    const int p    = px0 + tpx;         // stripe-local pixel
    const int srW  = rows * WW;

    #pragma unroll
    for (int gi = 0; gi < 2; gi++) {
        const int g = slot * 2 + gi;
        #pragma unroll 3
        for (int k = 0; k < 9; k++) {
            const int ch = g * 9 + k;
            const float dy = om[(size_t)ch * srW + p];
            const float dx = om[(size_t)(72 + ch) * srW + p];
            const float mm = om[(size_t)(144 + ch) * srW + p];
            const float mask = 1.f / (1.f + __expf(-mm));

            const float py = dy + (float)(h + k / 3 - 1);
            const float px = dx + (float)(wx + k % 3 - 1);
            const float y0f = floorf(py), x0f = floorf(px);
            const int y0 = (int)y0f, x0 = (int)x0f;
            const float ly = py - y0f, lx = px - x0f;

            float w00 = (1.f - ly) * (1.f - lx), w01 = (1.f - ly) * lx;
            float w10 = ly * (1.f - lx),         w11 = ly * lx;
            if (!((unsigned)y0       < (unsigned)HH && (unsigned)x0       < (unsigned)WW)) w00 = 0.f;
            if (!((unsigned)y0       < (unsigned)HH && (unsigned)(x0 + 1) < (unsigned)WW)) w01 = 0.f;
            if (!((unsigned)(y0 + 1) < (unsigned)HH && (unsigned)x0       < (unsigned)WW)) w10 = 0.f;
            if (!((unsigned)(y0 + 1) < (unsigned)HH && (unsigned)(x0 + 1) < (unsigned)WW)) w11 = 0.f;
            w00 *= mask; w01 *= mask; w10 *= mask; w11 *= mask;

            const int cy0 = min(max(y0, 0), HH - 1), cy1 = min(max(y0 + 1, 0), HH - 1);
            const int cx0 = min(max(x0, 0), WW - 1), cx1 = min(max(x0 + 1, 0), WW - 1);

            const u32x2 v00 = *(const u32x2*)(xpk + ((size_t)cy0 * WW + cx0) * CH + g * 4);
            const u32x2 v01 = *(const u32x2*)(xpk + ((size_t)cy0 * WW + cx1) * CH + g * 4);
            const u32x2 v10 = *(const u32x2*)(xpk + ((size_t)cy1 * WW + cx0) * CH + g * 4);
            const u32x2 v11 = *(const u32x2*)(xpk + ((size_t)cy1 * WW + cx1) * CH + g * 4);

            float vc[4];
            #pragma unroll
            for (int c = 0; c < 4; c++) {
                const int sh = (c & 1) * 16;
                const int wi = c >> 1;
                const float f00 = bf2f((v00[wi] >> sh) & 0xffffu);
                const float f01 = bf2f((v01[wi] >> sh) & 0xffffu);
                const float f10 = bf2f((v10[wi] >> sh) & 0xffffu);
                const float f11 = bf2f((v11[wi] >> sh) & 0xffffu);
                vc[c] = w00 * f00 + w01 * f01 + w10 * f10 + w11 * f11;
            }
            u32x2 vv;
            vv[0] = (uint32_t)f2bf(vc[0]) | ((uint32_t)f2bf(vc[1]) << 16);
            vv[1] = (uint32_t)f2bf(vc[2]) | ((uint32_t)f2bf(vc[3]) << 16);
            *(u32x2*)(V + tpx * VP + k * 32 + g * 4) = vv;
        }
    }
    __syncthreads();

    const int lane = tid & 63;
    const int nt   = tid >> 6;          // n-tile = wave
    const int tx   = lane & 15;
    const int q    = lane >> 4;

    f32x4 acc0 = (f32x4){0.f, 0.f, 0.f, 0.f};
    f32x4 acc1 = (f32x4){0.f, 0.f, 0.f, 0.f};
    #pragma unroll
    for (int s = 0; s < 9; s++) {
        const short8 bfr = *(const short8*)(V + (nt * 16 + tx) * VP + s * 32 + q * 8);
        const short8 a0 = *(const short8*)(wpk + (((size_t)s * 2 + 0) * 16 + tx) * 32 + q * 8);
        const short8 a1 = *(const short8*)(wpk + (((size_t)s * 2 + 1) * 16 + tx) * 32 + q * 8);
        acc0 = __builtin_amdgcn_mfma_f32_16x16x32_bf16(a0, bfr, acc0, 0, 0, 0);
        acc1 = __builtin_amdgcn_mfma_f32_16x16x32_bf16(a1, bfr, acc1, 0, 0, 0);
    }

    // epilogue: lane holds px = nt*16+tx, oc = mt*16 + q*4 + i
    const int pxo = nt * 16 + tx;
    uint16_t* drow = feapk + ((size_t)h * WW + (px0 & 255) + pxo) * CH;
    #pragma unroll
    for (int mt = 0; mt < 2; mt++) {
        const f32x4 a = mt ? acc1 : acc0;
        uint32_t wd[2];
        #pragma unroll
        for (int i2 = 0; i2 < 2; i2++) {
            float v0 = a[i2 * 2]     + b_dcn[mt * 16 + q * 4 + i2 * 2];
            float v1 = a[i2 * 2 + 1] + b_dcn[mt * 16 + q * 4 + i2 * 2 + 1];
            v0 = v0 > 0.f ? v0 : NEG_SLOPE * v0;
            v1 = v1 > 0.f ? v1 : NEG_SLOPE * v1;
            wd[i2] = (uint32_t)f2bf(v0) | ((uint32_t)f2bf(v1) << 16);
        }
        u32x2 vv = { wd[0], wd[1] };
        *(u32x2*)(drow + mt * 16 + q * 4) = vv;
    }
}

extern "C" void kernel_launch(void* const* d_in, const int* in_sizes, int n_in,
                              void* d_out, int out_size, void* d_ws, size_t ws_size,
                              hipStream_t stream) {
    const float* x      = (const float*)d_in[0];
    const float* offset = (const float*)d_in[1];
    const float* w_off  = (const float*)d_in[2];
    const float* b_off  = (const float*)d_in[3];
    const float* w_dcn  = (const float*)d_in[4];
    const float* b_dcn  = (const float*)d_in[5];
    const float* w_c1   = (const float*)d_in[6];
    const float* b_c1   = (const float*)d_in[7];
    float* out = (float*)d_out;

    auto aup = [](size_t v) { return (v + 255) & ~(size_t)255; };
    char* wsp = (char*)d_ws;
    uint16_t* xpk    = (uint16_t*)wsp; wsp += aup((size_t)BB * HW * CH * 2);
    uint16_t* offpk  = (uint16_t*)wsp; wsp += aup((size_t)BB * HW * CH * 2);
    uint16_t* feapk  = (uint16_t*)wsp; wsp += aup((size_t)BB * HW * CH * 2);
    uint16_t* wpkoff = (uint16_t*)wsp; wsp += aup((size_t)WPK_OFF_N * 2);
    uint16_t* wpkc1  = (uint16_t*)wsp; wsp += aup((size_t)WPK_C1_N * 2);
    uint16_t* wpkdcn = (uint16_t*)wsp; wsp += aup((size_t)WPK_DCN_N * 2);
    float*    om     = (float*)wsp;
    const size_t used = (size_t)(wsp - (char*)d_ws);

    const size_t row_bytes = (size_t)OMC * WW * sizeof(float);  // 221184
    const size_t avail = (ws_size > used) ? (ws_size - used) : 0;
    int rows_per = (int)(avail / row_bytes) & ~3;   // multiple of 4
    if (rows_per < 4)  rows_per = 4;
    if (rows_per > HH) rows_per = HH;

    // 0) packs
    pack_px<<<dim3(HW / 256, 4), dim3(256), 0, stream>>>(x, offset, xpk, offpk);
    const int wn = WPK_OFF_N + WPK_C1_N + WPK_DCN_N;
    pack_w<<<dim3((wn + 255) / 256), dim3(256), 0, stream>>>(
        w_off, w_c1, w_dcn, wpkoff, wpkc1, wpkdcn);

    // 1+2) per batch, per row-stripe: conv_off (MFMA) -> om, dcn (MFMA) -> feapk
    for (int b = 0; b < BB; b++) {
        const uint16_t* offb = offpk + (size_t)b * HW * CH;
        const uint16_t* xb   = xpk   + (size_t)b * HW * CH;
        uint16_t*       feab = feapk + (size_t)b * HW * CH;
        for (int r0 = 0; r0 < HH; r0 += rows_per) {
            const int rows = (r0 + rows_per <= HH) ? rows_per : (HH - r0);
            conv_off_mfma<<<dim3(WW / 16, rows / 4), dim3(256), 0, stream>>>(
                offb, wpkoff, b_off, om, r0, rows);
            dcn_mfma<<<dim3(rows * 4), dim3(256), 0, stream>>>(
                xb, om, wpkdcn, b_dcn, feab, r0, rows);
        }
    }

    // 3) conv c1 (MFMA) + bias + residual
    for (int b = 0; b < BB; b++) {
        conv_c1_mfma<<<dim3(WW / 16, HH / 8), dim3(256), 0, stream>>>(
            feapk + (size_t)b * HW * CH, wpkc1, b_c1,
            x + (size_t)b * CH * HW, out + (size_t)b * CH * HW);
    }
}